// Round 4
// baseline (1122.604 us; speedup 1.0000x reference)
//
#include <hip/hip_runtime.h>
#include <hip/hip_bf16.h>

#define BB 4
#define NN 50000
#define EE 160000
#define KK 1000
#define CH 128
#define TM 64
#define NTILES ((NN + TM - 1) / TM)   // 782
#define SCAN_CHUNK 2048
#define SCAN_NB ((NN + SCAN_CHUNK - 1) / SCAN_CHUNK)  // 25
#define FPAD 132                       // f32 accum row stride (bank-shift 4)

typedef unsigned short u16;
typedef unsigned int u32;
typedef unsigned char u8;
typedef __attribute__((ext_vector_type(8))) short short8;
typedef __attribute__((ext_vector_type(4))) float f32x4;

// bf16 XOR swizzle for [rows][128] u16 tiles (conflict-free ds_read_b128)
__device__ __forceinline__ int ZIDX(int m, int k) {
  return (m << 7) | (k ^ ((m & 7) << 3));
}

__device__ __forceinline__ u16 f2b(float f) {
  __hip_bfloat16 h = __float2bfloat16(f);   // RNE
  return *reinterpret_cast<u16*>(&h);
}
__device__ __forceinline__ float b2f(u32 lo16) {
  return __uint_as_float(lo16 << 16);
}

// ---------------------------------------------------------------------------
// CSR build
// ---------------------------------------------------------------------------
__global__ __launch_bounds__(256)
void csr_count(const int* __restrict__ edges, int* __restrict__ cnt) {
  int stride = gridDim.x * blockDim.x;
  for (int i = blockIdx.x * blockDim.x + threadIdx.x; i < BB * EE; i += stride) {
    int b = i / EE, e = i - b * EE;
    int dst = edges[(b * 2 + 1) * EE + e];
    atomicAdd(&cnt[b * NN + dst], 1);
  }
}

__global__ __launch_bounds__(256)
void scan_local(const int* __restrict__ cnt, int* __restrict__ offs,
                int* __restrict__ bsum) {
  __shared__ int sdata[256];
  const int g = blockIdx.y, blk = blockIdx.x, t = threadIdx.x;
  const int i0 = blk * SCAN_CHUNK + t * 8;
  int v[8];
  int s = 0;
#pragma unroll
  for (int j = 0; j < 8; ++j) {
    int i = i0 + j;
    v[j] = (i < NN) ? cnt[g * NN + i] : 0;
    s += v[j];
  }
  sdata[t] = s;
  __syncthreads();
#pragma unroll
  for (int off = 1; off < 256; off <<= 1) {
    int vv = (t >= off) ? sdata[t - off] : 0;
    __syncthreads();
    sdata[t] += vv;
    __syncthreads();
  }
  int run = sdata[t] - s;
#pragma unroll
  for (int j = 0; j < 8; ++j) {
    int i = i0 + j;
    if (i < NN) offs[g * (NN + 1) + i] = run;
    run += v[j];
  }
  if (t == 255) bsum[g * SCAN_NB + blk] = sdata[255];
}

__global__ __launch_bounds__(256)
void scan_add(int* __restrict__ offs, int* __restrict__ woff,
              const int* __restrict__ bsum) {
  const int g = blockIdx.y, blk = blockIdx.x, t = threadIdx.x;
  int boff = 0;
  for (int j = 0; j < blk; ++j) boff += bsum[g * SCAN_NB + j];
  const int i0 = blk * SCAN_CHUNK + t * 8;
#pragma unroll
  for (int j = 0; j < 8; ++j) {
    int i = i0 + j;
    if (i < NN) {
      int val = offs[g * (NN + 1) + i] + boff;
      offs[g * (NN + 1) + i] = val;
      woff[g * NN + i] = val;
    }
  }
  if (blk == SCAN_NB - 1 && t == 255)
    offs[g * (NN + 1) + NN] = boff + bsum[g * SCAN_NB + blk];
}

__global__ __launch_bounds__(256)
void csr_fill(const int* __restrict__ edges, int* __restrict__ woff,
              int* __restrict__ csr_src, u8* __restrict__ csr_dst) {
  int stride = gridDim.x * blockDim.x;
  for (int i = blockIdx.x * blockDim.x + threadIdx.x; i < BB * EE; i += stride) {
    int b = i / EE, e = i - b * EE;
    int src = edges[(b * 2) * EE + e];
    int dst = edges[(b * 2 + 1) * EE + e];
    int pos = atomicAdd(&woff[b * NN + dst], 1);
    csr_src[b * EE + pos] = src;
    csr_dst[b * EE + pos] = (u8)(dst & 63);   // tiles are 64-aligned
  }
}

// ---------------------------------------------------------------------------
// Weight prep: bf16, plain transposed [n][k] images (register-fragment loads).
// mats: 0:w2[0]  1:w1r[0]  2:w2[1]  3:w1r[1]  4:w2[2]
// ---------------------------------------------------------------------------
__global__ __launch_bounds__(256)
void prep_weights(const float* __restrict__ w1r, const float* __restrict__ w2,
                  u16* __restrict__ img) {
  int i = blockIdx.x * blockDim.x + threadIdx.x;
  if (i >= 5 * CH * CH) return;
  int mat = i >> 14, rem = i & 16383;
  int k = rem >> 7, n = rem & 127;
  const float* src;
  switch (mat) {
    case 0: src = w2; break;
    case 1: src = w1r; break;
    case 2: src = w2 + 16384; break;
    case 3: src = w1r + 16384; break;
    default: src = w2 + 32768; break;
  }
  img[(mat << 14) + (n << 7) + k] = f2b(src[(k << 7) + n]);
}

// ---------------------------------------------------------------------------
// Fused GIN layer. 256 thr (4 waves), tile 64 nodes x 128 ch.
// Gather: edge-parallel, LDS f32 atomics into zaccf[64][132].
// Weights: register fragments from img (L2).  LDS: 33.8KB -> 4 blk/CU.
// zt (bf16 A of GEMM2) and ot (output tile) overlay zaccf after GEMM1.
// ---------------------------------------------------------------------------
template <bool L0>
__global__ __launch_bounds__(256, 4)
void gin_layer(const void* __restrict__ hin_v, u16* __restrict__ hout,
               const int* __restrict__ offs, const int* __restrict__ csr_src,
               const u8* __restrict__ csr_dst,
               const float* __restrict__ w1f,       // L0 only (128)
               const u16* __restrict__ img_w1,      // !L0: transposed bf16
               const u16* __restrict__ img_w2,
               const float* __restrict__ b1v, const float* __restrict__ b2v) {
  __shared__ float zaccf[TM * FPAD];          // 33,792 B
  __shared__ float zacc0[L0 ? TM : 1];
  u16* zt = (u16*)zaccf;                      // bf16 [64][128] swz, bytes [0,16K)
  u16* ot = (u16*)zaccf + 8192;               // bytes [16K,32K)

  const int tid = threadIdx.x;
  const int lane = tid & 63;
  const int wv = tid >> 6;
  const int g = lane >> 4;
  const int lr = lane & 15;
  const int cb = wv * 32;

  const int b = blockIdx.x / NTILES;
  const int t0 = (blockIdx.x % NTILES) * TM;
  const int nm = min(TM, NN - t0);

  const int s0 = offs[b * (NN + 1) + t0];
  const int e0 = offs[b * (NN + 1) + min(t0 + TM, NN)];

  const int m = tid >> 2;
  const int p = tid & 3;

  // preload w2 fragments (both paths); w1 frags preloaded for !L0
  short8 fw2[2][4];
#pragma unroll
  for (int ct = 0; ct < 2; ++ct)
#pragma unroll
    for (int ks = 0; ks < 4; ++ks)
      fw2[ct][ks] = *(const short8*)&img_w2[((cb + (ct << 4) + lr) << 7) +
                                            (ks << 5) + (g << 3)];

  if (L0) {
    // ---- scalar gather (edge-parallel) ----
    const float* x = (const float*)hin_v;
    if (tid < TM) zacc0[tid] = (tid < nm) ? x[b * NN + t0 + tid] : 0.f;
    __syncthreads();
    {
      int M = e0 - s0;
      int Mw = (M + 3) >> 2;
      int wstart = s0 + wv * Mw;
      int wend = min(wstart + Mw, e0);
      for (int e = wstart + lane; e < wend; e += 64) {
        int src = csr_src[b * EE + e];
        int dstl = csr_dst[b * EE + e];
        unsafeAtomicAdd(&zacc0[dstl], x[b * NN + src]);
      }
    }
    __syncthreads();
    // ---- t = relu(z0 * w1f + b1), direct to zt ----
    {
      float z0 = zacc0[m];
#pragma unroll
      for (int jj = 0; jj < 4; ++jj) {
        int c0 = (p << 5) + (jj << 3);
        short8 tv;
#pragma unroll
        for (int t = 0; t < 8; ++t)
          tv[t] = (short)f2b(fmaxf(z0 * w1f[c0 + t] + b1v[c0 + t], 0.f));
        *(short8*)&zt[ZIDX(m, c0)] = tv;
      }
    }
    __syncthreads();
  } else {
    const u16* h = (const u16*)hin_v;
    // ---- self-init zaccf (coalesced) ----
    if (m < nm) {
      const uint4* hr =
          (const uint4*)(h + ((size_t)(b * NN + t0 + m) << 7)) + (p << 2);
      float* zr = &zaccf[m * FPAD + (p << 5)];
#pragma unroll
      for (int j = 0; j < 4; ++j) {
        uint4 v = hr[j];
        zr[j * 8 + 0] = b2f(v.x & 0xffff); zr[j * 8 + 1] = b2f(v.x >> 16);
        zr[j * 8 + 2] = b2f(v.y & 0xffff); zr[j * 8 + 3] = b2f(v.y >> 16);
        zr[j * 8 + 4] = b2f(v.z & 0xffff); zr[j * 8 + 5] = b2f(v.z >> 16);
        zr[j * 8 + 6] = b2f(v.w & 0xffff); zr[j * 8 + 7] = b2f(v.w >> 16);
      }
    } else {
      float* zr = &zaccf[m * FPAD + (p << 5)];
#pragma unroll
      for (int j = 0; j < 32; ++j) zr[j] = 0.f;
    }
    __syncthreads();

    // ---- edge-parallel gather: striped so concurrent lanes hit distinct dst
    {
      int M = e0 - s0;
      int Mw = (M + 3) >> 2;                 // edges per wave
      int wstart = s0 + wv * Mw;
      int wend = min(wstart + Mw, e0);
      int Mww = wend - wstart;
      if (Mww > 0) {
        int R = (Mww + 15) >> 4;
        int g4 = lane >> 2;                  // 16 edge-groups per wave
        for (int r = 0; r < R; ++r) {
          int ei = g4 * R + r;
          if (ei < Mww) {
            int e = wstart + ei;
            int src = csr_src[b * EE + e];
            int dstl = csr_dst[b * EE + e];
            const uint4* hr =
                (const uint4*)(h + ((size_t)(b * NN + src) << 7)) + (p << 2);
            float* zr = &zaccf[dstl * FPAD + (p << 5)];
#pragma unroll
            for (int j = 0; j < 4; ++j) {
              uint4 v = hr[j];
              unsafeAtomicAdd(&zr[j * 8 + 0], b2f(v.x & 0xffff));
              unsafeAtomicAdd(&zr[j * 8 + 1], b2f(v.x >> 16));
              unsafeAtomicAdd(&zr[j * 8 + 2], b2f(v.y & 0xffff));
              unsafeAtomicAdd(&zr[j * 8 + 3], b2f(v.y >> 16));
              unsafeAtomicAdd(&zr[j * 8 + 4], b2f(v.z & 0xffff));
              unsafeAtomicAdd(&zr[j * 8 + 5], b2f(v.z >> 16));
              unsafeAtomicAdd(&zr[j * 8 + 6], b2f(v.w & 0xffff));
              unsafeAtomicAdd(&zr[j * 8 + 7], b2f(v.w >> 16));
            }
          }
        }
      }
    }
    __syncthreads();

    // ---- GEMM1: t = relu(z @ w1 + b1); A read from f32 zaccf + convert
    short8 fw1[2][4];
#pragma unroll
    for (int ct = 0; ct < 2; ++ct)
#pragma unroll
      for (int ks = 0; ks < 4; ++ks)
        fw1[ct][ks] = *(const short8*)&img_w1[((cb + (ct << 4) + lr) << 7) +
                                              (ks << 5) + (g << 3)];
    f32x4 a1[4][2];
#pragma unroll
    for (int rt = 0; rt < 4; ++rt)
#pragma unroll
      for (int ct = 0; ct < 2; ++ct) a1[rt][ct] = (f32x4){0.f, 0.f, 0.f, 0.f};
#pragma unroll
    for (int ks = 0; ks < 4; ++ks) {
      int kb = (ks << 5) + (g << 3);
      short8 af[4];
#pragma unroll
      for (int rt = 0; rt < 4; ++rt) {
        const float* zr = &zaccf[((rt << 4) + lr) * FPAD + kb];
        f32x4 lo = *(const f32x4*)zr;
        f32x4 hi = *(const f32x4*)(zr + 4);
        short8 a;
        a[0] = (short)f2b(lo[0]); a[1] = (short)f2b(lo[1]);
        a[2] = (short)f2b(lo[2]); a[3] = (short)f2b(lo[3]);
        a[4] = (short)f2b(hi[0]); a[5] = (short)f2b(hi[1]);
        a[6] = (short)f2b(hi[2]); a[7] = (short)f2b(hi[3]);
        af[rt] = a;
      }
#pragma unroll
      for (int rt = 0; rt < 4; ++rt)
#pragma unroll
        for (int ct = 0; ct < 2; ++ct)
          a1[rt][ct] = __builtin_amdgcn_mfma_f32_16x16x32_bf16(
              af[rt], fw1[ct][ks], a1[rt][ct], 0, 0, 0);
    }
    __syncthreads();   // all zaccf reads done before zt overlay writes

    // ---- t -> zt (bf16 swizzled, overlays zaccf)
#pragma unroll
    for (int rt = 0; rt < 4; ++rt)
#pragma unroll
      for (int ct = 0; ct < 2; ++ct) {
        int col = cb + (ct << 4) + lr;
        float bias = b1v[col];
#pragma unroll
        for (int r = 0; r < 4; ++r) {
          int row = (rt << 4) + (g << 2) + r;
          zt[ZIDX(row, col)] = f2b(fmaxf(a1[rt][ct][r] + bias, 0.f));
        }
      }
    __syncthreads();
  }

  // ---- GEMM2: o = relu(t @ w2 + b2), A from bf16 zt
  f32x4 a2[4][2];
#pragma unroll
  for (int rt = 0; rt < 4; ++rt)
#pragma unroll
    for (int ct = 0; ct < 2; ++ct) a2[rt][ct] = (f32x4){0.f, 0.f, 0.f, 0.f};
#pragma unroll
  for (int ks = 0; ks < 4; ++ks) {
    int kb = (ks << 5) + (g << 3);
    short8 af[4];
#pragma unroll
    for (int rt = 0; rt < 4; ++rt)
      af[rt] = *(const short8*)&zt[ZIDX((rt << 4) + lr, kb)];
#pragma unroll
    for (int rt = 0; rt < 4; ++rt)
#pragma unroll
      for (int ct = 0; ct < 2; ++ct)
        a2[rt][ct] = __builtin_amdgcn_mfma_f32_16x16x32_bf16(
            af[rt], fw2[ct][ks], a2[rt][ct], 0, 0, 0);
  }

  // ---- o -> ot (disjoint LDS region; no barrier needed before writes)
#pragma unroll
  for (int rt = 0; rt < 4; ++rt)
#pragma unroll
    for (int ct = 0; ct < 2; ++ct) {
      int col = cb + (ct << 4) + lr;
      float bias = b2v[col];
#pragma unroll
      for (int r = 0; r < 4; ++r) {
        int row = (rt << 4) + (g << 2) + r;
        ot[ZIDX(row, col)] = f2b(fmaxf(a2[rt][ct][r] + bias, 0.f));
      }
    }
  __syncthreads();

  // ---- coalesced copy-out
  for (int i = tid; i < 1024; i += 256) {
    int mm = i >> 4, c0 = (i & 15) << 3;
    if (mm < nm) {
      uint4 v = *(const uint4*)&ot[ZIDX(mm, c0)];
      *(uint4*)&hout[(((size_t)(b * NN + t0 + mm)) << 7) + c0] = v;
    }
  }
}

// ---------------------------------------------------------------------------
// Heads (emb is bf16)
// ---------------------------------------------------------------------------
__global__ __launch_bounds__(256)
void heads_kernel(const u16* __restrict__ emb, const int* __restrict__ didx,
                  const int* __restrict__ nopp, const float* __restrict__ pol_w,
                  const float* __restrict__ pol_b, const float* __restrict__ val_w,
                  const float* __restrict__ val_b, float* __restrict__ out) {
  int gw = (blockIdx.x * blockDim.x + threadIdx.x) >> 6;
  int lane = threadIdx.x & 63;
  if (gw >= BB * KK) return;
  int b = gw / KK, k = gw - b * KK;
  int node = didx[b * KK + k];
  const u16* e = emb + (((size_t)(b * NN + node)) << 7);
  u32 v = *(const u32*)&e[lane << 1];
  float f0 = __uint_as_float(v << 16);
  float f1 = __uint_as_float(v & 0xffff0000u);
  float s = f0 * pol_w[lane << 1] + f1 * pol_w[(lane << 1) + 1];
#pragma unroll
  for (int off = 32; off; off >>= 1) s += __shfl_down(s, off);
  if (lane == 0) out[b * KK + k] = s + pol_b[0];
  if (k == nopp[0]) {
    float vv = f0 * val_w[lane << 1] + f1 * val_w[(lane << 1) + 1];
#pragma unroll
    for (int off = 32; off; off >>= 1) vv += __shfl_down(vv, off);
    if (lane == 0) out[BB * KK + b] = vv + val_b[0];
  }
}

// ---------------------------------------------------------------------------
extern "C" void kernel_launch(void* const* d_in, const int* in_sizes, int n_in,
                              void* d_out, int out_size, void* d_ws, size_t ws_size,
                              hipStream_t stream) {
  const float* x     = (const float*)d_in[0];
  const int*   edges = (const int*)d_in[1];
  const int*   didx  = (const int*)d_in[2];
  const int*   nopp  = (const int*)d_in[3];
  const float* w1f   = (const float*)d_in[4];
  const float* w1r   = (const float*)d_in[5];
  const float* w2    = (const float*)d_in[6];
  const float* b1    = (const float*)d_in[7];
  const float* b2    = (const float*)d_in[8];
  const float* pol_w = (const float*)d_in[9];
  const float* pol_b = (const float*)d_in[10];
  const float* val_w = (const float*)d_in[11];
  const float* val_b = (const float*)d_in[12];
  float* out = (float*)d_out;

  char* ws = (char*)d_ws;
  u16* hA = (u16*)ws;            ws += (size_t)BB * NN * CH * 2;   // 51.2 MB
  u16* hB = (u16*)ws;            ws += (size_t)BB * NN * CH * 2;   // 51.2 MB
  u16* img = (u16*)ws;           ws += (size_t)5 * CH * CH * 2;    // 160 KB
  int* offs = (int*)ws;          ws += (size_t)BB * (NN + 1) * 4;
  int* woff = (int*)ws;          ws += (size_t)BB * NN * 4;
  int* cnt  = (int*)ws;          ws += (size_t)BB * NN * 4;
  int* bsum = (int*)ws;          ws += (size_t)BB * SCAN_NB * 4;
  int* csr  = (int*)ws;          ws += (size_t)BB * EE * 4;
  u8*  csrd = (u8*)ws;           ws += (size_t)BB * EE;

  hipMemsetAsync(cnt, 0, (size_t)BB * NN * 4, stream);
  prep_weights<<<(5 * CH * CH + 255) / 256, 256, 0, stream>>>(w1r, w2, img);
  csr_count<<<1250, 256, 0, stream>>>(edges, cnt);
  scan_local<<<dim3(SCAN_NB, BB), 256, 0, stream>>>(cnt, offs, bsum);
  scan_add<<<dim3(SCAN_NB, BB), 256, 0, stream>>>(offs, woff, bsum);
  csr_fill<<<1250, 256, 0, stream>>>(edges, woff, csr, csrd);

  const int tiles = BB * NTILES;
  gin_layer<true><<<tiles, 256, 0, stream>>>(
      x, hA, offs, csr, csrd, w1f, nullptr, img, b1, b2);
  gin_layer<false><<<tiles, 256, 0, stream>>>(
      hA, hB, offs, csr, csrd, nullptr, img + 1 * 16384, img + 2 * 16384,
      b1 + CH, b2 + CH);
  gin_layer<false><<<tiles, 256, 0, stream>>>(
      hB, hA, offs, csr, csrd, nullptr, img + 3 * 16384, img + 4 * 16384,
      b1 + 2 * CH, b2 + 2 * CH);

  heads_kernel<<<(BB * KK * 64 + 255) / 256, 256, 0, stream>>>(
      hA, didx, nopp, pol_w, pol_b, val_w, val_b, out);
}